// Round 2
// baseline (87.419 us; speedup 1.0000x reference)
//
#include <hip/hip_runtime.h>

#define BB 32
#define CC 1024
#define QQ 128
#define EE 512

typedef unsigned int uint32;
typedef unsigned short u16;
typedef __bf16 bf16x8 __attribute__((ext_vector_type(8)));
typedef float f32x4 __attribute__((ext_vector_type(4)));

// workspace layout (bytes)
#define QM_OFF   (0u)                        // bf16 [B][Q][E]  (question * ws_m)
#define QT_OFF   (4u<<20)                    // bf16 [B][E][Q]  (question transposed)
#define QDOT_OFF (8u<<20)                    // f32  [B][Q]     (question . ws_q)
#define MT_OFF   (QDOT_OFF + BB*QQ*4u)       // f32  [B][16]    (per-tile max)
#define ST_OFF   (MT_OFF + BB*16*4u)         // f32  [B][16]    (per-tile expsum)
#define PV_OFF   (ST_OFF + BB*16*4u)         // f32  [B][16][E] (per-tile weighted ctx)

__device__ __forceinline__ u16 f2bf(float f){
  uint32 u = __builtin_bit_cast(uint32, f);
  u += 0x7fffu + ((u >> 16) & 1u);           // RNE; inputs are finite
  return (u16)(u >> 16);
}
__device__ __forceinline__ float bf2f(uint32 lo16){
  return __builtin_bit_cast(float, lo16 << 16);
}

// ---------------- prep A: qm = bf16(q * ws_m), qdot = q . ws_q ----------------
__global__ __launch_bounds__(64) void k_prep_row(const float* __restrict__ q,
                                                 const float* __restrict__ ws,
                                                 unsigned char* __restrict__ wsp){
  const int row  = blockIdx.x;               // b*QQ + qi
  const int lane = threadIdx.x;              // 0..63, each lane: 8 elements
  const float4* qr = (const float4*)(q + (size_t)row*EE) + lane*2;
  const float4* wq = (const float4*)(ws) + lane*2;
  const float4* wm = (const float4*)(ws + 2*EE) + lane*2;
  float4 v0 = qr[0], v1 = qr[1];
  float4 a0 = wq[0], a1 = wq[1];
  float4 m0 = wm[0], m1 = wm[1];
  uint4 u;
  u.x = f2bf(v0.x*m0.x) | ((uint32)f2bf(v0.y*m0.y) << 16);
  u.y = f2bf(v0.z*m0.z) | ((uint32)f2bf(v0.w*m0.w) << 16);
  u.z = f2bf(v1.x*m1.x) | ((uint32)f2bf(v1.y*m1.y) << 16);
  u.w = f2bf(v1.z*m1.z) | ((uint32)f2bf(v1.w*m1.w) << 16);
  *(uint4*)(wsp + QM_OFF + (size_t)row*EE*2 + lane*16) = u;
  float dot = v0.x*a0.x + v0.y*a0.y + v0.z*a0.z + v0.w*a0.w
            + v1.x*a1.x + v1.y*a1.y + v1.z*a1.z + v1.w*a1.w;
  #pragma unroll
  for (int off=32; off; off>>=1) dot += __shfl_xor(dot, off);
  if (lane == 0) ((float*)(wsp + QDOT_OFF))[row] = dot;
}

// ---------------- prep B: qT[b][e][q] = bf16(question[b][q][e]) ----------------
__global__ __launch_bounds__(256) void k_prep_t(const float* __restrict__ q,
                                                unsigned char* __restrict__ wsp){
  const int b = blockIdx.x >> 2, ec = blockIdx.x & 3, e0 = ec*128;
  __shared__ u16 tile[128*132];              // [q][e], pad 132 to break conflicts
  const int tid = threadIdx.x;
  #pragma unroll
  for (int i=0;i<16;i++){
    int id = tid + i*256;                    // 0..4095
    int qi = id >> 5;                        // 0..127
    int ex = (id & 31) << 2;                 // 0..124
    float4 v = *(const float4*)(q + (size_t)(b*QQ + qi)*EE + e0 + ex);
    u16* t = &tile[qi*132 + ex];
    t[0]=f2bf(v.x); t[1]=f2bf(v.y); t[2]=f2bf(v.z); t[3]=f2bf(v.w);
  }
  __syncthreads();
  #pragma unroll
  for (int i=0;i<8;i++){
    int id = tid + i*256;                    // 0..2047
    int er = id >> 4;                        // 0..127 (e row)
    int qc = (id & 15) << 3;                 // 0..120 (q chunk of 8)
    uint4 u;
    u.x = (uint32)tile[(qc+0)*132 + er] | ((uint32)tile[(qc+1)*132 + er] << 16);
    u.y = (uint32)tile[(qc+2)*132 + er] | ((uint32)tile[(qc+3)*132 + er] << 16);
    u.z = (uint32)tile[(qc+4)*132 + er] | ((uint32)tile[(qc+5)*132 + er] << 16);
    u.w = (uint32)tile[(qc+6)*132 + er] | ((uint32)tile[(qc+7)*132 + er] << 16);
    *(uint4*)(wsp + QT_OFF + ((size_t)(b*EE + e0 + er)*QQ + qc)*2) = u;
  }
}

// ---------------- main: sim -> softmax -> c2q + fused q2c partials ----------------
// 512 blocks (2/CU), 256 threads (4 waves), 64 ctx rows/block.
// K chunked into 4x128, double-buffered LDS; staging of chunk c+1 overlaps GEMM1(c).
__global__ __launch_bounds__(256, 2) void k_main(const float* __restrict__ ctx,
                                                 const float* __restrict__ ws,
                                                 unsigned char* __restrict__ wsp,
                                                 float* __restrict__ out){
  __shared__ __align__(16) unsigned char Ab[2][16384]; // chunk bf16 [64][128] swizzled; Ab[0] later = P [64][128]
  __shared__ float qd_s[QQ];
  __shared__ float cd_s[64];
  __shared__ float mx_s[64];
  __shared__ float rden_s[64];
  __shared__ float warr_s[64];

  const int bid = blockIdx.x;
  const int sw  = (bid & 7)*64 + (bid >> 3); // XCD-contiguous swizzle (512 % 8 == 0); 4 full batches per XCD
  const int b   = sw >> 4;
  const int t_  = sw & 15;
  const int c0  = t_ << 6;
  const int tid = threadIdx.x;
  const int lane = tid & 63;
  const int w    = tid >> 6;
  const int l15  = lane & 15;
  const int l4   = lane >> 4;

  if (tid < QQ) qd_s[tid] = ((const float*)(wsp + QDOT_OFF))[b*QQ + tid];

  // staging map: thread -> (row 0..63, kseg 0..3 of 32 floats)
  const int srow = tid >> 2;
  const int kseg = tid & 3;
  const float* crow = ctx + (size_t)(b*CC + c0 + srow)*EE + kseg*32;
  const float* wrow = ws + EE + kseg*32;     // ws_c
  const int sswz = (srow & 7) << 4;

  float4 sv[8], wv[8];
  float cdreg = 0.f;

  auto stage_load = [&](int c){
    const float4* p  = (const float4*)(crow + c*128);
    const float4* wq = (const float4*)(wrow + c*128);
    #pragma unroll
    for (int j=0;j<8;j++){ sv[j] = p[j]; wv[j] = wq[j]; }
  };
  auto stage_store = [&](int c){
    unsigned char* dst = Ab[c&1] + srow*256;
    #pragma unroll
    for (int j2=0;j2<4;j2++){
      float4 x = sv[2*j2], y = sv[2*j2+1];
      float4 a = wv[2*j2], d = wv[2*j2+1];
      cdreg += x.x*a.x + x.y*a.y + x.z*a.z + x.w*a.w
             + y.x*d.x + y.y*d.y + y.z*d.z + y.w*d.w;   // f32 cdot rides along
      uint4 u;
      u.x = f2bf(x.x) | ((uint32)f2bf(x.y)<<16);
      u.y = f2bf(x.z) | ((uint32)f2bf(x.w)<<16);
      u.z = f2bf(y.x) | ((uint32)f2bf(y.y)<<16);
      u.w = f2bf(y.z) | ((uint32)f2bf(y.w)<<16);
      *(uint4*)(dst + ((kseg*64 + j2*16) ^ sswz)) = u;
    }
  };

  stage_load(0); stage_store(0);
  __syncthreads();

  // GEMM1: sim[64][128] = ctx_bf16 . qm^T, K chunked (4 x 128), double-buffered
  f32x4 acc[8];
  #pragma unroll
  for (int n=0;n<8;n++) acc[n] = (f32x4){0.f,0.f,0.f,0.f};

  const int arow = w*16 + l15;
  const int aswz = (arow & 7) << 4;
  const uint4* qm4 = (const uint4*)(wsp + QM_OFF);
  const size_t qmb0 = (size_t)(b*QQ + l15)*64 + l4;   // uint4 units

  #pragma unroll
  for (int c=0;c<4;c++){
    if (c<3) stage_load(c+1);                // issue HBM loads early (overlap with GEMM1)
    const unsigned char* abase = Ab[c&1] + arow*256;
    #pragma unroll
    for (int ks=0; ks<4; ks++){
      bf16x8 af = __builtin_bit_cast(bf16x8,
          *(const uint4*)(abase + ((ks*64 + l4*16) ^ aswz)));
      #pragma unroll
      for (int n=0;n<8;n++){
        bf16x8 bq = __builtin_bit_cast(bf16x8, qm4[qmb0 + (size_t)n*1024 + c*16 + ks*4]);
        acc[n] = __builtin_amdgcn_mfma_f32_16x16x32_bf16(af, bq, acc[n], 0, 0, 0);
      }
    }
    if (c<3) stage_store(c+1);
    __syncthreads();
  }

  // cdot reduce over the 4 ksegs of each row (same wave)
  cdreg += __shfl_xor(cdreg, 1);
  cdreg += __shfl_xor(cdreg, 2);
  if (kseg == 0) cd_s[srow] = cdreg;         // written+read within same wave (rows 16w..16w+15)

  // softmax over q (wave-local rows); P bf16 -> Ab[0] (swizzled)
  #pragma unroll
  for (int r=0;r<4;r++){
    const int row = w*16 + l4*4 + r;         // D-layout: row=(lane>>4)*4+reg
    const float cd = cd_s[row];
    float v[8];
    float mx = -3.0e38f;
    #pragma unroll
    for (int n=0;n<8;n++){
      v[n] = acc[n][r] + cd + qd_s[n*16 + l15];
      mx = fmaxf(mx, v[n]);
    }
    mx = fmaxf(mx, __shfl_xor(mx, 1));
    mx = fmaxf(mx, __shfl_xor(mx, 2));
    mx = fmaxf(mx, __shfl_xor(mx, 4));
    mx = fmaxf(mx, __shfl_xor(mx, 8));
    const int rswz = (row & 7) << 4;
    float sum = 0.f;
    #pragma unroll
    for (int n=0;n<8;n++){
      float p = __expf(v[n] - mx);
      u16 h = f2bf(p);
      sum += bf2f(h);                        // denom over bf16-rounded p (consistent with GEMM2)
      *(u16*)(Ab[0] + row*256 + (((n*16 + l15)*2) ^ rswz)) = h;
    }
    sum += __shfl_xor(sum, 1);
    sum += __shfl_xor(sum, 2);
    sum += __shfl_xor(sum, 4);
    sum += __shfl_xor(sum, 8);
    if (l15 == 0){
      rden_s[row] = 1.f / sum;
      mx_s[row] = mx;
    }
  }
  __syncthreads();

  // q2c weights for this 64-row tile (wave 0)
  if (tid < 64){
    float mv = mx_s[tid];
    float M = mv;
    #pragma unroll
    for (int off=32; off; off>>=1) M = fmaxf(M, __shfl_xor(M, off));
    float wv_ = __expf(mv - M);
    warr_s[tid] = wv_;
    float S = wv_;
    #pragma unroll
    for (int off=32; off; off>>=1) S += __shfl_xor(S, off);
    if (tid == 0){
      ((float*)(wsp + MT_OFF))[b*16 + t_] = M;
      ((float*)(wsp + ST_OFF))[b*16 + t_] = S;
    }
  }
  __syncthreads();

  // fused q2c partial: re-read own ctx tile (L2/L3-hot), coalesced float2/lane
  {
    const float2* cb = (const float2*)(ctx + (size_t)(b*CC + c0)*EE) + tid; // e-pair 2*tid
    float a0 = 0.f, a1 = 0.f;
    #pragma unroll 8
    for (int c=0;c<64;c++){
      float2 g = cb[(size_t)c*256];
      float wv_ = warr_s[c];
      a0 = fmaf(wv_, g.x, a0);
      a1 = fmaf(wv_, g.y, a1);
    }
    float* pv = (float*)(wsp + PV_OFF) + (size_t)(b*16 + t_)*EE;
    float2 r2; r2.x = a0; r2.y = a1;
    *(float2*)(pv + 2*tid) = r2;
  }

  // GEMM2: c2q[64][512] = P . question, split into 2 e-halves (VGPR cap)
  const uint4* qt4 = (const uint4*)(wsp + QT_OFF);
  float* ob = out + (size_t)(b*CC + c0)*EE;
  #pragma unroll
  for (int h=0; h<2; h++){
    const int e0 = h*256 + w*64;
    f32x4 acc2[4][4];
    #pragma unroll
    for (int m=0;m<4;m++){
      #pragma unroll
      for (int n=0;n<4;n++) acc2[m][n] = (f32x4){0.f,0.f,0.f,0.f};
    }
    #pragma unroll
    for (int ks=0; ks<4; ks++){
      bf16x8 a[4];
      #pragma unroll
      for (int m=0;m<4;m++){
        const int row = m*16 + l15;
        a[m] = __builtin_bit_cast(bf16x8,
          *(const uint4*)(Ab[0] + row*256 + ((ks*64 + l4*16) ^ ((row & 7) << 4))));
      }
      #pragma unroll
      for (int n=0;n<4;n++){
        const int e = e0 + n*16 + l15;
        bf16x8 bq = __builtin_bit_cast(bf16x8, qt4[(size_t)(b*EE + e)*16 + ks*4 + l4]);
        #pragma unroll
        for (int m=0;m<4;m++)
          acc2[m][n] = __builtin_amdgcn_mfma_f32_16x16x32_bf16(a[m], bq, acc2[m][n], 0, 0, 0);
      }
    }
    #pragma unroll
    for (int m=0;m<4;m++){
      #pragma unroll
      for (int r=0;r<4;r++){
        const int row = m*16 + l4*4 + r;
        const float rd = rden_s[row];
        #pragma unroll
        for (int n=0;n<4;n++)
          ob[(size_t)row*EE + e0 + n*16 + l15] = acc2[m][n][r] * rd;
      }
    }
  }
}

// ------------- q2c combine: rescale 16 tile-partials per batch -------------
__global__ __launch_bounds__(256) void k_q2c_fin(unsigned char* __restrict__ wsp,
                                                 float* __restrict__ out){
  const int b = blockIdx.x;
  __shared__ float sc[16];
  const int tid = threadIdx.x;
  if (tid == 0){
    const float* Mt = (const float*)(wsp + MT_OFF) + b*16;
    const float* St = (const float*)(wsp + ST_OFF) + b*16;
    float M = -3.0e38f;
    for (int t=0;t<16;t++) M = fmaxf(M, Mt[t]);
    float den = 0.f;
    float e[16];
    for (int t=0;t<16;t++){ e[t] = __expf(Mt[t]-M); den += e[t]*St[t]; }
    float rd = 1.f/den;
    for (int t=0;t<16;t++) sc[t] = e[t]*rd;
  }
  __syncthreads();
  const float* pv = (const float*)(wsp + PV_OFF) + (size_t)b*16*EE;
  float a0 = 0.f, a1 = 0.f;
  #pragma unroll
  for (int t=0;t<16;t++){
    a0 = fmaf(sc[t], pv[t*EE + tid],       a0);
    a1 = fmaf(sc[t], pv[t*EE + tid + 256], a1);
  }
  size_t base = (size_t)BB*CC*EE + (size_t)b*EE;
  out[base + tid]       = a0;
  out[base + tid + 256] = a1;
}

extern "C" void kernel_launch(void* const* d_in, const int* in_sizes, int n_in,
                              void* d_out, int out_size, void* d_ws, size_t ws_size,
                              hipStream_t stream){
  const float* ctx = (const float*)d_in[0];
  const float* q   = (const float*)d_in[1];
  const float* ws  = (const float*)d_in[2];
  float* out = (float*)d_out;
  unsigned char* wsp = (unsigned char*)d_ws;

  k_prep_row<<<dim3(BB*QQ), dim3(64),  0, stream>>>(q, ws, wsp);
  k_prep_t  <<<dim3(BB*4),  dim3(256), 0, stream>>>(q, wsp);
  k_main    <<<dim3(512),   dim3(256), 0, stream>>>(ctx, ws, wsp, out);
  k_q2c_fin <<<dim3(BB),    dim3(256), 0, stream>>>(wsp, out);
}

// Round 3
// 73.801 us; speedup vs baseline: 1.1845x; 1.1845x over previous
//
#include <hip/hip_runtime.h>

#define BB 32
#define CC 1024
#define QQ 128
#define EE 512

typedef unsigned int uint32;
typedef unsigned short u16;
typedef __bf16 bf16x8 __attribute__((ext_vector_type(8)));
typedef float f32x4 __attribute__((ext_vector_type(4)));

// workspace layout (bytes), total ~12.4 MB
#define QMF_OFF  (0u)                  // bf16 frag-major: [b][ks 0..15][nf 0..7][lane 0..63][8]
#define QTF_OFF  (4u<<20)              // bf16 frag-major: [b][ks2 0..3][ne 0..31][lane][8]
#define PV_OFF   (8u<<20)              // f32 [b][64 groups][512]
#define QD_OFF   (12u<<20)             // f32 [b][128]
#define MT_OFF   ((12u<<20) + 16384u)  // f32 [b][64]
#define ST_OFF   (MT_OFF + 8192u)      // f32 [b][64]

__device__ __forceinline__ u16 bfc(float f){
  __bf16 h = (__bf16)f;                // HW v_cvt (RNE)
  return __builtin_bit_cast(u16, h);
}

// ---- prep: qmf = bf16(q * ws_m) in GEMM1 B-fragment-major layout ----
// frag (b,ks,nf): value[lane][j] = q[b][nf*16 + (lane&15)][ks*32 + (lane>>4)*8 + j] * ws_m[k]
__global__ __launch_bounds__(256) void k_prep_qm(const float* __restrict__ q,
                                                 const float* __restrict__ ws,
                                                 unsigned char* __restrict__ wsp){
  const int b = blockIdx.x >> 2, et = blockIdx.x & 3, e0 = et*128;
  __shared__ u16 tile[128*136];        // [q][e-local], pad 136 (272B row: 16B-aligned, 2-way banks)
  const int tid = threadIdx.x;
  #pragma unroll
  for (int i=0;i<16;i++){
    int id = tid + i*256;              // 4096 float4 chunks
    int qi = id >> 5;
    int el = (id & 31) << 2;
    float4 v = *(const float4*)(q + (size_t)(b*QQ+qi)*EE + e0 + el);
    float4 m = *(const float4*)(ws + 2*EE + e0 + el);
    ushort4 u; u.x = bfc(v.x*m.x); u.y = bfc(v.y*m.y); u.z = bfc(v.z*m.z); u.w = bfc(v.w*m.w);
    *(ushort4*)&tile[qi*136 + el] = u;
  }
  __syncthreads();
  const int lane = tid & 63, wv = tid >> 6, l15 = lane & 15, l4 = lane >> 4;
  uint4* qmf = (uint4*)(wsp + QMF_OFF);
  #pragma unroll
  for (int i=0;i<8;i++){
    int f = wv*8 + i;                  // 32 frags per block
    int kl = f >> 3, nf = f & 7;
    uint4 u = *(const uint4*)&tile[(nf*16 + l15)*136 + kl*32 + l4*8];
    qmf[(size_t)((b*16 + et*4 + kl)*8 + nf)*64 + lane] = u;
  }
}

// ---- prep: qtf = bf16(q) in GEMM2 B-fragment-major layout ----
// frag (b,ks2,ne): value[lane][j] = q[b][ks2*32 + (lane>>4)*8 + j][ne*16 + (lane&15)]
__global__ __launch_bounds__(256) void k_prep_qt(const float* __restrict__ q,
                                                 unsigned char* __restrict__ wsp){
  const int b = blockIdx.x >> 2, et = blockIdx.x & 3, e0 = et*128;
  __shared__ u16 tile[128*136];        // [q][e-local] raw bf16
  const int tid = threadIdx.x;
  #pragma unroll
  for (int i=0;i<16;i++){
    int id = tid + i*256;
    int qi = id >> 5;
    int el = (id & 31) << 2;
    float4 v = *(const float4*)(q + (size_t)(b*QQ+qi)*EE + e0 + el);
    ushort4 u; u.x = bfc(v.x); u.y = bfc(v.y); u.z = bfc(v.z); u.w = bfc(v.w);
    *(ushort4*)&tile[qi*136 + el] = u;
  }
  __syncthreads();
  const int lane = tid & 63, wv = tid >> 6, l15 = lane & 15, l4 = lane >> 4;
  uint4* qtf = (uint4*)(wsp + QTF_OFF);
  #pragma unroll
  for (int i=0;i<8;i++){
    int f = wv*8 + i;
    int ks2 = f >> 3, nl = f & 7, ne = et*8 + nl;
    uint32 x[4];
    #pragma unroll
    for (int p=0;p<4;p++){             // gather transpose: 8 strided u16 reads
      u16 t0 = tile[(ks2*32 + l4*8 + 2*p    )*136 + nl*16 + l15];
      u16 t1 = tile[(ks2*32 + l4*8 + 2*p + 1)*136 + nl*16 + l15];
      x[p] = (uint32)t0 | ((uint32)t1 << 16);
    }
    uint4 u; u.x = x[0]; u.y = x[1]; u.z = x[2]; u.w = x[3];
    qtf[(size_t)((b*4 + ks2)*32 + ne)*64 + lane] = u;
  }
}

// ---- prep: qdot[row] = q[row] . ws_q ----
__global__ __launch_bounds__(256) void k_prep_qd(const float* __restrict__ q,
                                                 const float* __restrict__ ws,
                                                 unsigned char* __restrict__ wsp){
  const int row = blockIdx.x*4 + (threadIdx.x >> 6);
  const int lane = threadIdx.x & 63;
  const float4* qr = (const float4*)(q + (size_t)row*EE) + lane*2;
  const float4* wq = (const float4*)ws + lane*2;
  float4 v0 = qr[0], v1 = qr[1], a0 = wq[0], a1 = wq[1];
  float dot = v0.x*a0.x + v0.y*a0.y + v0.z*a0.z + v0.w*a0.w
            + v1.x*a1.x + v1.y*a1.y + v1.z*a1.z + v1.w*a1.w;
  #pragma unroll
  for (int off=1; off<64; off<<=1) dot += __shfl_xor(dot, off);
  if (lane == 0) ((float*)(wsp + QD_OFF))[row] = dot;
}

// ---- main: 1024 blocks x 4 waves; block = 32 ctx rows; wave = 16 rows x (q- or e-)half.
// Wave-local everything except 2 barriers (max exchange, P exchange). No LDS staging of A:
// A-frags loaded f32 direct from global, converted in-reg; all B ops are coalesced frag loads.
__global__ __launch_bounds__(256, 4) void k_main(const float* __restrict__ ctx,
                                                 const float* __restrict__ ws,
                                                 unsigned char* __restrict__ wsp,
                                                 float* __restrict__ out){
  __shared__ __align__(16) u16 pfrag[2][4][512];  // [rg][ks2][GEMM2 A-frag: lane*8+j] (8KB)
  __shared__ float cd_s[2][2][16];
  __shared__ float smax_s[2][2][16];
  __shared__ float ssum_s[2][2][16];
  __shared__ float wrow_s[2][2][16];

  const int bid = blockIdx.x;
  const int sw  = (bid & 7)*128 + (bid >> 3);  // XCD-contiguous (1024%8==0): 4 batches/XCD
  const int b   = sw >> 5;
  const int t   = sw & 31;
  const int tid = threadIdx.x;
  const int lane = tid & 63;
  const int w    = tid >> 6;
  const int rg   = w >> 1;                     // row-group (16 rows)
  const int h    = w & 1;                      // q-half (GEMM1) / e-half (GEMM2)
  const int l15  = lane & 15;
  const int l4   = lane >> 4;
  const int r0   = t*32 + rg*16;

  // qdot for this wave's q-cols (issue early; L2-hot)
  const float* qdp = (const float*)(wsp + QD_OFF) + b*QQ + h*64 + l15;
  float qd[4];
  #pragma unroll
  for (int n=0;n<4;n++) qd[n] = qdp[n*16];

  // ---- GEMM1: sim[16][64] = ctx_rows . qm^T(half h); cdot rides on the f32 A data ----
  const float* arow = ctx + (size_t)(b*CC + r0 + l15)*EE + l4*8;
  const float* wsc  = ws + EE + l4*8;
  const uint4* qmf  = (const uint4*)(wsp + QMF_OFF) + (size_t)b*8192 + h*256 + lane;
  f32x4 acc[4];
  #pragma unroll
  for (int n=0;n<4;n++) acc[n] = (f32x4){0.f,0.f,0.f,0.f};
  float cdp = 0.f;
  #pragma unroll 4
  for (int ks=0; ks<16; ks++){
    float4 a0 = *(const float4*)(arow + ks*32);
    float4 a1 = *(const float4*)(arow + ks*32 + 4);
    float4 c0 = *(const float4*)(wsc + ks*32);
    float4 c1 = *(const float4*)(wsc + ks*32 + 4);
    cdp += a0.x*c0.x + a0.y*c0.y + a0.z*c0.z + a0.w*c0.w
         + a1.x*c1.x + a1.y*c1.y + a1.z*c1.z + a1.w*c1.w;
    bf16x8 af;
    af[0]=(__bf16)a0.x; af[1]=(__bf16)a0.y; af[2]=(__bf16)a0.z; af[3]=(__bf16)a0.w;
    af[4]=(__bf16)a1.x; af[5]=(__bf16)a1.y; af[6]=(__bf16)a1.z; af[7]=(__bf16)a1.w;
    #pragma unroll
    for (int n=0;n<4;n++){
      bf16x8 bq = __builtin_bit_cast(bf16x8, qmf[(ks*8 + n)*64]);
      acc[n] = __builtin_amdgcn_mfma_f32_16x16x32_bf16(af, bq, acc[n], 0, 0, 0);
    }
  }
  // cdot: lane partial is (row=l15, k-slice l4) -> reduce over l4, move to D-layout via LDS (wave-local)
  cdp += __shfl_xor(cdp, 16);
  cdp += __shfl_xor(cdp, 32);
  if (l4 == 0) cd_s[rg][h][l15] = cdp;

  // ---- softmax (half): v = sim + cdot + qdot; half-row max -> LDS ----
  float mxh[4];
  #pragma unroll
  for (int r=0;r<4;r++){
    const float cdr = cd_s[rg][h][l4*4 + r];   // D-layout row = l4*4+r
    float m = -3.0e38f;
    #pragma unroll
    for (int n=0;n<4;n++){
      float v = acc[n][r] + cdr + qd[n];
      acc[n][r] = v;
      m = fmaxf(m, v);
    }
    m = fmaxf(m, __shfl_xor(m,1));
    m = fmaxf(m, __shfl_xor(m,2));
    m = fmaxf(m, __shfl_xor(m,4));
    m = fmaxf(m, __shfl_xor(m,8));
    mxh[r] = m;
  }
  if (l15 == 0){
    #pragma unroll
    for (int r=0;r<4;r++) smax_s[rg][h][l4*4 + r] = mxh[r];
  }
  __syncthreads();                              // barrier 1: max exchange across q-halves
  float mx[4];
  #pragma unroll
  for (int r=0;r<4;r++) mx[r] = fmaxf(smax_s[rg][0][l4*4+r], smax_s[rg][1][l4*4+r]);

  // exp; write P into pfrag (GEMM2 A-frag layout); half-sums
  const int l4p = l15 >> 3;
  const int jj  = l15 & 7;
  #pragma unroll
  for (int r=0;r<4;r++){
    float s = 0.f;
    #pragma unroll
    for (int n=0;n<4;n++){
      float p = __expf(acc[n][r] - mx[r]);
      __bf16 hb = (__bf16)p;
      s += (float)hb;                          // denom over bf16-rounded p (consistent with GEMM2)
      // q = 64h + n*16 + l15 -> ks2 = 2h+(n>>1), sub = ((n&1)<<1)|l4p, j = jj, P-row = l4*4+r
      pfrag[rg][(h<<1) + (n>>1)][ ((((n&1)<<1)|l4p)*16 + l4*4 + r)*8 + jj ] = __builtin_bit_cast(u16, hb);
    }
    s += __shfl_xor(s,1); s += __shfl_xor(s,2); s += __shfl_xor(s,4); s += __shfl_xor(s,8);
    if (l15 == 0) ssum_s[rg][h][l4*4 + r] = s;
  }

  // q2c stats for this 16-row group (wave-local; both h-waves compute identical values)
  float m16 = fmaxf(fmaxf(mx[0],mx[1]), fmaxf(mx[2],mx[3]));
  m16 = fmaxf(m16, __shfl_xor(m16,16));
  m16 = fmaxf(m16, __shfl_xor(m16,32));
  float wr[4], s16 = 0.f;
  #pragma unroll
  for (int r=0;r<4;r++){ wr[r] = __expf(mx[r] - m16); s16 += wr[r]; }
  s16 += __shfl_xor(s16,16);
  s16 += __shfl_xor(s16,32);
  if (l15 == 0){
    #pragma unroll
    for (int r=0;r<4;r++) wrow_s[rg][h][l4*4 + r] = wr[r];
  }
  if (h == 0 && lane == 0){
    ((float*)(wsp + MT_OFF))[b*64 + t*2 + rg] = m16;
    ((float*)(wsp + ST_OFF))[b*64 + t*2 + rg] = s16;
  }
  __syncthreads();                              // barrier 2: P + sums exchanged
  float rden[4];
  #pragma unroll
  for (int r=0;r<4;r++) rden[r] = 1.f/(ssum_s[rg][0][l4*4+r] + ssum_s[rg][1][l4*4+r]);

  // ---- GEMM2: c2q rows r0..+15, e-half h (two 128-col passes to cap VGPR) ----
  const uint4* qt4 = (const uint4*)(wsp + QTF_OFF) + (size_t)b*8192 + lane;
  const uint4* pf  = (const uint4*)&pfrag[rg][0][0];
  float* ob = out + (size_t)(b*CC + r0)*EE + h*256;
  #pragma unroll
  for (int pp=0; pp<2; pp++){
    f32x4 acc2[8];
    #pragma unroll
    for (int n2=0;n2<8;n2++) acc2[n2] = (f32x4){0.f,0.f,0.f,0.f};
    #pragma unroll
    for (int ks2=0; ks2<4; ks2++){
      bf16x8 a = __builtin_bit_cast(bf16x8, pf[ks2*64 + lane]);
      #pragma unroll
      for (int n2=0;n2<8;n2++){
        const int ne = h*16 + pp*8 + n2;
        bf16x8 bq = __builtin_bit_cast(bf16x8, qt4[(ks2*32 + ne)*64]);
        acc2[n2] = __builtin_amdgcn_mfma_f32_16x16x32_bf16(a, bq, acc2[n2], 0, 0, 0);
      }
    }
    #pragma unroll
    for (int n2=0;n2<8;n2++){
      #pragma unroll
      for (int r=0;r<4;r++)
        ob[(size_t)(l4*4 + r)*EE + pp*128 + n2*16 + l15] = acc2[n2][r]*rden[r];
    }
  }

  // ---- fused q2c partial: rows rg*16..+15 x e-half h (L2/L3-hot re-read) ----
  {
    const float4* cb = (const float4*)(ctx + (size_t)(b*CC + r0)*EE + h*256) + lane;
    float4 a4; a4.x = 0.f; a4.y = 0.f; a4.z = 0.f; a4.w = 0.f;
    #pragma unroll
    for (int rr=0; rr<16; rr++){
      float wv = wrow_s[rg][h][rr];
      float4 g = cb[(size_t)rr*128];
      a4.x = fmaf(wv, g.x, a4.x); a4.y = fmaf(wv, g.y, a4.y);
      a4.z = fmaf(wv, g.z, a4.z); a4.w = fmaf(wv, g.w, a4.w);
    }
    float* pv = (float*)(wsp + PV_OFF) + (size_t)(b*64 + t*2 + rg)*EE + h*256 + lane*4;
    *(float4*)pv = a4;
  }
}

// ---- q2c combine: 64 group-partials per batch ----
__global__ __launch_bounds__(256) void k_fin(unsigned char* __restrict__ wsp,
                                             float* __restrict__ out){
  const int b = blockIdx.x;
  __shared__ float sc_s[64];
  const int tid = threadIdx.x;
  if (tid < 64){
    float Mg = ((const float*)(wsp + MT_OFF))[b*64 + tid];
    float Sg = ((const float*)(wsp + ST_OFF))[b*64 + tid];
    float M = Mg;
    #pragma unroll
    for (int off=1; off<64; off<<=1) M = fmaxf(M, __shfl_xor(M, off));
    float ev = __expf(Mg - M);
    float ds = ev * Sg;
    #pragma unroll
    for (int off=1; off<64; off<<=1) ds += __shfl_xor(ds, off);
    sc_s[tid] = ev / ds;
  }
  __syncthreads();
  const float* pv = (const float*)(wsp + PV_OFF) + (size_t)b*64*EE;
  float a0 = 0.f, a1 = 0.f;
  #pragma unroll 8
  for (int g=0; g<64; g++){
    float s = sc_s[g];
    a0 = fmaf(s, pv[g*EE + tid],       a0);
    a1 = fmaf(s, pv[g*EE + tid + 256], a1);
  }
  size_t base = (size_t)BB*CC*EE + (size_t)b*EE;
  out[base + tid]       = a0;
  out[base + tid + 256] = a1;
}

extern "C" void kernel_launch(void* const* d_in, const int* in_sizes, int n_in,
                              void* d_out, int out_size, void* d_ws, size_t ws_size,
                              hipStream_t stream){
  const float* ctx = (const float*)d_in[0];
  const float* q   = (const float*)d_in[1];
  const float* ws  = (const float*)d_in[2];
  float* out = (float*)d_out;
  unsigned char* wsp = (unsigned char*)d_ws;

  k_prep_qm<<<dim3(BB*4),    dim3(256), 0, stream>>>(q, ws, wsp);
  k_prep_qt<<<dim3(BB*4),    dim3(256), 0, stream>>>(q, wsp);
  k_prep_qd<<<dim3(BB*QQ/4), dim3(256), 0, stream>>>(q, ws, wsp);
  k_main   <<<dim3(1024),    dim3(256), 0, stream>>>(ctx, ws, wsp, out);
  k_fin    <<<dim3(BB),      dim3(256), 0, stream>>>(wsp, out);
}

// Round 4
// 62.641 us; speedup vs baseline: 1.3956x; 1.1781x over previous
//
#include <hip/hip_runtime.h>

#define BB 32
#define CC 1024
#define QQ 128
#define EE 512

typedef unsigned int uint32;
typedef unsigned short u16;
typedef __bf16 bf16x8 __attribute__((ext_vector_type(8)));
typedef float f32x4 __attribute__((ext_vector_type(4)));

// workspace layout (bytes)
#define QMF_OFF  (0u)                  // bf16 frag-major: [b][ks 0..15][nf 0..7][lane][8]  (qm' = q*ws_m + ws_c)
#define QTF_OFF  (4u<<20)              // bf16 frag-major: [b][ks2 0..3][ne 0..31][lane][8]
#define PV_OFF   (8u<<20)              // f32 [b][64 groups][512]
#define QD_OFF   (12u<<20)             // f32 [b][128]
#define MT_OFF   ((12u<<20) + 16384u)  // f32 [b][64]
#define ST_OFF   (MT_OFF + 8192u)      // f32 [b][64]

__device__ __forceinline__ u16 bfc(float f){
  __bf16 h = (__bf16)f;                // HW v_cvt (RNE)
  return __builtin_bit_cast(u16, h);
}

// ---- prep: qmf = bf16(q*ws_m + ws_c) in GEMM1 B-fragment-major layout ----
// folding ws_c: sim = ctx . qm'  ==  (ctx.q*wm) + (ctx.wc)  -> cdot eliminated in k_main
__global__ __launch_bounds__(256) void k_prep_qm(const float* __restrict__ q,
                                                 const float* __restrict__ ws,
                                                 unsigned char* __restrict__ wsp){
  const int b = blockIdx.x >> 2, et = blockIdx.x & 3, e0 = et*128;
  __shared__ u16 tile[128*136];
  const int tid = threadIdx.x;
  #pragma unroll
  for (int i=0;i<16;i++){
    int id = tid + i*256;
    int qi = id >> 5;
    int el = (id & 31) << 2;
    float4 v = *(const float4*)(q + (size_t)(b*QQ+qi)*EE + e0 + el);
    float4 m = *(const float4*)(ws + 2*EE + e0 + el);
    float4 c = *(const float4*)(ws +   EE + e0 + el);
    ushort4 u; u.x = bfc(v.x*m.x + c.x); u.y = bfc(v.y*m.y + c.y);
               u.z = bfc(v.z*m.z + c.z); u.w = bfc(v.w*m.w + c.w);
    *(ushort4*)&tile[qi*136 + el] = u;
  }
  __syncthreads();
  const int lane = tid & 63, wv = tid >> 6, l15 = lane & 15, l4 = lane >> 4;
  uint4* qmf = (uint4*)(wsp + QMF_OFF);
  #pragma unroll
  for (int i=0;i<8;i++){
    int f = wv*8 + i;
    int kl = f >> 3, nf = f & 7;
    uint4 u = *(const uint4*)&tile[(nf*16 + l15)*136 + kl*32 + l4*8];
    qmf[(size_t)((b*16 + et*4 + kl)*8 + nf)*64 + lane] = u;
  }
}

// ---- prep: qtf = bf16(q) in GEMM2 B-fragment-major layout ----
__global__ __launch_bounds__(256) void k_prep_qt(const float* __restrict__ q,
                                                 unsigned char* __restrict__ wsp){
  const int b = blockIdx.x >> 2, et = blockIdx.x & 3, e0 = et*128;
  __shared__ u16 tile[128*136];
  const int tid = threadIdx.x;
  #pragma unroll
  for (int i=0;i<16;i++){
    int id = tid + i*256;
    int qi = id >> 5;
    int el = (id & 31) << 2;
    float4 v = *(const float4*)(q + (size_t)(b*QQ+qi)*EE + e0 + el);
    ushort4 u; u.x = bfc(v.x); u.y = bfc(v.y); u.z = bfc(v.z); u.w = bfc(v.w);
    *(ushort4*)&tile[qi*136 + el] = u;
  }
  __syncthreads();
  const int lane = tid & 63, wv = tid >> 6, l15 = lane & 15, l4 = lane >> 4;
  uint4* qtf = (uint4*)(wsp + QTF_OFF);
  #pragma unroll
  for (int i=0;i<8;i++){
    int f = wv*8 + i;
    int ks2 = f >> 3, nl = f & 7, ne = et*8 + nl;
    uint32 x[4];
    #pragma unroll
    for (int p=0;p<4;p++){
      u16 t0 = tile[(ks2*32 + l4*8 + 2*p    )*136 + nl*16 + l15];
      u16 t1 = tile[(ks2*32 + l4*8 + 2*p + 1)*136 + nl*16 + l15];
      x[p] = (uint32)t0 | ((uint32)t1 << 16);
    }
    uint4 u; u.x = x[0]; u.y = x[1]; u.z = x[2]; u.w = x[3];
    qtf[(size_t)((b*4 + ks2)*32 + ne)*64 + lane] = u;
  }
}

// ---- prep: qdot[row] = q[row] . ws_q (exact f32) ----
__global__ __launch_bounds__(256) void k_prep_qd(const float* __restrict__ q,
                                                 const float* __restrict__ ws,
                                                 unsigned char* __restrict__ wsp){
  const int row = blockIdx.x*4 + (threadIdx.x >> 6);
  const int lane = threadIdx.x & 63;
  const float4* qr = (const float4*)(q + (size_t)row*EE) + lane*2;
  const float4* wq = (const float4*)ws + lane*2;
  float4 v0 = qr[0], v1 = qr[1], a0 = wq[0], a1 = wq[1];
  float dot = v0.x*a0.x + v0.y*a0.y + v0.z*a0.z + v0.w*a0.w
            + v1.x*a1.x + v1.y*a1.y + v1.z*a1.z + v1.w*a1.w;
  #pragma unroll
  for (int off=1; off<64; off<<=1) dot += __shfl_xor(dot, off);
  if (lane == 0) ((float*)(wsp + QD_OFF))[row] = dot;
}

// ---- main: 1024 blocks x 4 waves; block = 32 ctx rows; wave = 16 rows x q/e-half.
// A staged f32 via global_load_lds (contiguous, source-XOR-swizzled), double-buffered
// K-chunks of 64: stage(c+1) issued BEFORE compute(c) so HBM latency hides under MFMA.
__global__ __launch_bounds__(256, 4) void k_main(const float* __restrict__ ctx,
                                                 unsigned char* __restrict__ wsp,
                                                 float* __restrict__ out){
  __shared__ __align__(16) unsigned char Ast[2][8192]; // f32 chunk [32 rows][16 parts of 16B]; Ast[0] later = pfrag
  __shared__ float smax_s[2][2][16];
  __shared__ float ssum_s[2][2][16];
  __shared__ float wrow_s[2][2][16];

  const int bid = blockIdx.x;
  const int sw  = (bid & 7)*128 + (bid >> 3);  // XCD-contiguous (1024%8==0)
  const int b   = sw >> 5;
  const int t   = sw & 31;
  const int tid = threadIdx.x;
  const int lane = tid & 63;
  const int w    = tid >> 6;
  const int rg   = w >> 1;
  const int h    = w & 1;
  const int l15  = lane & 15;
  const int l4   = lane >> 4;
  const int r0   = t*32 + rg*16;

  // qdot for this wave's q-cols (L2-hot)
  const float* qdp = (const float*)(wsp + QD_OFF) + b*QQ + h*64 + l15;
  float qd[4];
  #pragma unroll
  for (int n=0;n<4;n++) qd[n] = qdp[n*16];

  // staging source offsets (bytes): inst j covers rows j*16+w*4+(lane>>4), part lane&15,
  // source part pre-XOR-swizzled so the linear LDS dest reads back conflict-free
  const unsigned char* cbase = (const unsigned char*)(ctx + (size_t)(b*CC + t*32)*EE);
  int srcoff[2];
  #pragma unroll
  for (int j=0;j<2;j++){
    int row = j*16 + w*4 + (lane>>4);
    int gp  = (lane & 15) ^ (row & 7);
    srcoff[j] = row*2048 + gp*16;
  }
  auto stage = [&](int c){
    unsigned char* bufb = Ast[c & 1];
    #pragma unroll
    for (int j=0;j<2;j++){
      const unsigned char* g = cbase + srcoff[j] + c*256;
      __builtin_amdgcn_global_load_lds(
        (const __attribute__((address_space(1))) uint32*)g,
        (__attribute__((address_space(3))) uint32*)(bufb + j*4096 + w*1024),
        16, 0, 0);
    }
  };

  // ---- GEMM1: sim[16][64] = ctx . qm'^T  (A from LDS f32->bf16, B frag-major from L2) ----
  f32x4 acc[4];
  #pragma unroll
  for (int n=0;n<4;n++) acc[n] = (f32x4){0.f,0.f,0.f,0.f};
  const int arow = rg*16 + l15;
  const int a7   = arow & 7;
  const uint4* qmf = (const uint4*)(wsp + QMF_OFF) + (size_t)b*8192 + h*256 + lane;

  stage(0);
  __syncthreads();
  #pragma unroll
  for (int c=0; c<8; c++){
    if (c < 7) stage(c+1);                   // issue next chunk early; overlaps compute below
    const unsigned char* ab = Ast[c&1] + arow*256;
    #pragma unroll
    for (int s=0; s<2; s++){
      uint4 f0 = *(const uint4*)(ab + ((s*8 + ((l4*2+0) ^ a7))*16));
      uint4 f1 = *(const uint4*)(ab + ((s*8 + ((l4*2+1) ^ a7))*16));
      const float* p0 = (const float*)&f0;
      const float* p1 = (const float*)&f1;
      bf16x8 af;
      af[0]=(__bf16)p0[0]; af[1]=(__bf16)p0[1]; af[2]=(__bf16)p0[2]; af[3]=(__bf16)p0[3];
      af[4]=(__bf16)p1[0]; af[5]=(__bf16)p1[1]; af[6]=(__bf16)p1[2]; af[7]=(__bf16)p1[3];
      #pragma unroll
      for (int n=0;n<4;n++){
        bf16x8 bq = __builtin_bit_cast(bf16x8, qmf[((c*2+s)*8 + n)*64]);
        acc[n] = __builtin_amdgcn_mfma_f32_16x16x32_bf16(af, bq, acc[n], 0, 0, 0);
      }
    }
    __syncthreads();                          // vmcnt drain waits stage(c+1): had full compute to land
  }

  // ---- softmax (q-half): v = sim + qdot; half-row max -> LDS ----
  float mxh[4];
  #pragma unroll
  for (int r=0;r<4;r++){
    float m = -3.0e38f;
    #pragma unroll
    for (int n=0;n<4;n++){
      float v = acc[n][r] + qd[n];
      acc[n][r] = v;
      m = fmaxf(m, v);
    }
    m = fmaxf(m, __shfl_xor(m,1));
    m = fmaxf(m, __shfl_xor(m,2));
    m = fmaxf(m, __shfl_xor(m,4));
    m = fmaxf(m, __shfl_xor(m,8));
    mxh[r] = m;
  }
  if (l15 == 0){
    #pragma unroll
    for (int r=0;r<4;r++) smax_s[rg][h][l4*4 + r] = mxh[r];
  }
  __syncthreads();                             // barrier: max exchange (also: all Ast reads done)
  float mx[4];
  #pragma unroll
  for (int r=0;r<4;r++) mx[r] = fmaxf(smax_s[rg][0][l4*4+r], smax_s[rg][1][l4*4+r]);

  // exp; write P into pfrag (GEMM2 A-frag layout, overlaying Ast[0]); half-sums
  u16* pfr = (u16*)Ast[0];                     // [rg][ks2][512] u16 = 8KB
  const int l4p = l15 >> 3;
  const int jj  = l15 & 7;
  #pragma unroll
  for (int r=0;r<4;r++){
    float s = 0.f;
    #pragma unroll
    for (int n=0;n<4;n++){
      float p = __expf(acc[n][r] - mx[r]);
      __bf16 hb = (__bf16)p;
      s += (float)hb;
      pfr[(rg*4 + (h<<1) + (n>>1))*512 + ((((n&1)<<1)|l4p)*16 + l4*4 + r)*8 + jj] = __builtin_bit_cast(u16, hb);
    }
    s += __shfl_xor(s,1); s += __shfl_xor(s,2); s += __shfl_xor(s,4); s += __shfl_xor(s,8);
    if (l15 == 0) ssum_s[rg][h][l4*4 + r] = s;
  }

  // q2c stats for this 16-row group (wave-local)
  float m16 = fmaxf(fmaxf(mx[0],mx[1]), fmaxf(mx[2],mx[3]));
  m16 = fmaxf(m16, __shfl_xor(m16,16));
  m16 = fmaxf(m16, __shfl_xor(m16,32));
  float wr[4], s16 = 0.f;
  #pragma unroll
  for (int r=0;r<4;r++){ wr[r] = __expf(mx[r] - m16); s16 += wr[r]; }
  s16 += __shfl_xor(s16,16);
  s16 += __shfl_xor(s16,32);
  if (l15 == 0){
    #pragma unroll
    for (int r=0;r<4;r++) wrow_s[rg][h][l4*4 + r] = wr[r];
  }
  if (h == 0 && lane == 0){
    ((float*)(wsp + MT_OFF))[b*64 + t*2 + rg] = m16;
    ((float*)(wsp + ST_OFF))[b*64 + t*2 + rg] = s16;
  }
  __syncthreads();                             // barrier: P + sums exchanged
  float rden[4];
  #pragma unroll
  for (int r=0;r<4;r++) rden[r] = 1.f/(ssum_s[rg][0][l4*4+r] + ssum_s[rg][1][l4*4+r]);

  // ---- GEMM2: c2q rows r0..+15, e-half h ----
  const uint4* qt4 = (const uint4*)(wsp + QTF_OFF) + (size_t)b*8192 + lane;
  const uint4* pf  = (const uint4*)(Ast[0] + rg*4096);
  float* ob = out + (size_t)(b*CC + r0)*EE + h*256;
  #pragma unroll
  for (int pp=0; pp<2; pp++){
    f32x4 acc2[8];
    #pragma unroll
    for (int n2=0;n2<8;n2++) acc2[n2] = (f32x4){0.f,0.f,0.f,0.f};
    #pragma unroll
    for (int ks2=0; ks2<4; ks2++){
      bf16x8 a = __builtin_bit_cast(bf16x8, pf[ks2*64 + lane]);
      #pragma unroll
      for (int n2=0;n2<8;n2++){
        const int ne = h*16 + pp*8 + n2;
        bf16x8 bq = __builtin_bit_cast(bf16x8, qt4[(ks2*32 + ne)*64]);
        acc2[n2] = __builtin_amdgcn_mfma_f32_16x16x32_bf16(a, bq, acc2[n2], 0, 0, 0);
      }
    }
    #pragma unroll
    for (int n2=0;n2<8;n2++){
      #pragma unroll
      for (int r=0;r<4;r++)
        ob[(size_t)(l4*4 + r)*EE + pp*128 + n2*16 + l15] = acc2[n2][r]*rden[r];
    }
  }

  // ---- fused q2c partial: rows r0..+15 x e-half h (L2/L3-hot re-read) ----
  {
    const float4* cb = (const float4*)(ctx + (size_t)(b*CC + r0)*EE + h*256) + lane;
    float4 a4; a4.x = 0.f; a4.y = 0.f; a4.z = 0.f; a4.w = 0.f;
    #pragma unroll
    for (int rr=0; rr<16; rr++){
      float wv = wrow_s[rg][h][rr];
      float4 g = cb[(size_t)rr*128];
      a4.x = fmaf(wv, g.x, a4.x); a4.y = fmaf(wv, g.y, a4.y);
      a4.z = fmaf(wv, g.z, a4.z); a4.w = fmaf(wv, g.w, a4.w);
    }
    float* pv = (float*)(wsp + PV_OFF) + (size_t)(b*64 + t*2 + rg)*EE + h*256 + lane*4;
    *(float4*)pv = a4;
  }
}

// ---- q2c combine: 64 group-partials per batch ----
__global__ __launch_bounds__(256) void k_fin(unsigned char* __restrict__ wsp,
                                             float* __restrict__ out){
  const int b = blockIdx.x;
  __shared__ float sc_s[64];
  const int tid = threadIdx.x;
  if (tid < 64){
    float Mg = ((const float*)(wsp + MT_OFF))[b*64 + tid];
    float Sg = ((const float*)(wsp + ST_OFF))[b*64 + tid];
    float M = Mg;
    #pragma unroll
    for (int off=1; off<64; off<<=1) M = fmaxf(M, __shfl_xor(M, off));
    float ev = __expf(Mg - M);
    float ds = ev * Sg;
    #pragma unroll
    for (int off=1; off<64; off<<=1) ds += __shfl_xor(ds, off);
    sc_s[tid] = ev / ds;
  }
  __syncthreads();
  const float* pv = (const float*)(wsp + PV_OFF) + (size_t)b*64*EE;
  float a0 = 0.f, a1 = 0.f;
  #pragma unroll 8
  for (int g=0; g<64; g++){
    float s = sc_s[g];
    a0 = fmaf(s, pv[g*EE + tid],       a0);
    a1 = fmaf(s, pv[g*EE + tid + 256], a1);
  }
  size_t base = (size_t)BB*CC*EE + (size_t)b*EE;
  out[base + tid]       = a0;
  out[base + tid + 256] = a1;
}

extern "C" void kernel_launch(void* const* d_in, const int* in_sizes, int n_in,
                              void* d_out, int out_size, void* d_ws, size_t ws_size,
                              hipStream_t stream){
  const float* ctx = (const float*)d_in[0];
  const float* q   = (const float*)d_in[1];
  const float* ws  = (const float*)d_in[2];
  float* out = (float*)d_out;
  unsigned char* wsp = (unsigned char*)d_ws;

  k_prep_qm<<<dim3(BB*4),    dim3(256), 0, stream>>>(q, ws, wsp);
  k_prep_qt<<<dim3(BB*4),    dim3(256), 0, stream>>>(q, wsp);
  k_prep_qd<<<dim3(BB*QQ/4), dim3(256), 0, stream>>>(q, ws, wsp);
  k_main   <<<dim3(1024),    dim3(256), 0, stream>>>(ctx, wsp, out);
  k_fin    <<<dim3(BB),      dim3(256), 0, stream>>>(wsp, out);
}